// Round 1
// baseline (8325.531 us; speedup 1.0000x reference)
//
#include <hip/hip_runtime.h>

// Problem constants (fixed by reference setup_inputs)
#define BB 2
#define LQ 2048
#define SK 2048
#define CH 1024
#define NH 16
#define HD 64
#define ATT_SCALE 0.125f   // 1/sqrt(64)

// ---------------------------------------------------------------------------
// Complex GEMM:  yr = xr@wr - xi@wi ;  yi = xr@wi + xi@wr
// x: (M,K) row-major, w: (K,N) row-major, y: (M,N) row-major
// Tile: BM=64, BN=64, BK=16; 256 threads; 4x4 microtile per thread (x2 outputs)
// ---------------------------------------------------------------------------
template <bool ADD_BIAS>
__global__ __launch_bounds__(256) void cgemm_kernel(
    const float* __restrict__ xr, const float* __restrict__ xi,
    const float* __restrict__ wr, const float* __restrict__ wi,
    float* __restrict__ yr, float* __restrict__ yi,
    const float* __restrict__ br, const float* __restrict__ bi,
    int M, int N, int K)
{
    __shared__ float sXr[64][17];
    __shared__ float sXi[64][17];
    __shared__ float sWr[16][65];
    __shared__ float sWi[16][65];

    const int t  = threadIdx.x;
    const int tx = t & 15;
    const int ty = t >> 4;
    const int m0 = blockIdx.y * 64;
    const int n0 = blockIdx.x * 64;

    float accr[4][4] = {};
    float acci[4][4] = {};

    for (int k0 = 0; k0 < K; k0 += 16) {
        // X tiles: 64 rows x 16 k (1024 elems, 4 per thread, per array)
        #pragma unroll
        for (int rep = 0; rep < 4; rep++) {
            int idx = rep * 256 + t;
            int r = idx >> 4, c = idx & 15;
            size_t g = (size_t)(m0 + r) * K + k0 + c;
            sXr[r][c] = xr[g];
            sXi[r][c] = xi[g];
        }
        // W tiles: 16 k x 64 cols (coalesced 256B rows)
        #pragma unroll
        for (int rep = 0; rep < 4; rep++) {
            int idx = rep * 256 + t;
            int r = idx >> 6, c = idx & 63;
            size_t g = (size_t)(k0 + r) * N + n0 + c;
            sWr[r][c] = wr[g];
            sWi[r][c] = wi[g];
        }
        __syncthreads();

        #pragma unroll
        for (int kk = 0; kk < 16; kk++) {
            float ar[4], ai[4], wr_[4], wi_[4];
            #pragma unroll
            for (int i = 0; i < 4; i++) {
                ar[i] = sXr[ty * 4 + i][kk];
                ai[i] = sXi[ty * 4 + i][kk];
            }
            #pragma unroll
            for (int j = 0; j < 4; j++) {
                wr_[j] = sWr[kk][tx * 4 + j];
                wi_[j] = sWi[kk][tx * 4 + j];
            }
            #pragma unroll
            for (int i = 0; i < 4; i++) {
                #pragma unroll
                for (int j = 0; j < 4; j++) {
                    accr[i][j] += ar[i] * wr_[j] - ai[i] * wi_[j];
                    acci[i][j] += ar[i] * wi_[j] + ai[i] * wr_[j];
                }
            }
        }
        __syncthreads();
    }

    #pragma unroll
    for (int i = 0; i < 4; i++) {
        int m = m0 + ty * 4 + i;
        #pragma unroll
        for (int j = 0; j < 4; j++) {
            int n = n0 + tx * 4 + j;
            float vr_ = accr[i][j], vi_ = acci[i][j];
            if (ADD_BIAS) { vr_ += br[n]; vi_ += bi[n]; }
            yr[(size_t)m * N + n] = vr_;
            yi[(size_t)m * N + n] = vi_;
        }
    }
}

// ---------------------------------------------------------------------------
// Flash-style complex cross attention.
// Per block: one (b, h, 64-row Q tile). Online softmax over S in chunks of 32.
// Scores use concatenated head dim 128 (qr|qi vs kr|ki) => qr.kr + qi.ki.
// Thread layout: 256 threads = 16(tx) x 16(ty); each wave owns 16 Q rows
// (4 per ty); row-wise reductions via __shfl_xor within 16-lane tx groups.
// ---------------------------------------------------------------------------
__global__ __launch_bounds__(256) void attn_kernel(
    const float* __restrict__ qr, const float* __restrict__ qi,
    const float* __restrict__ kr, const float* __restrict__ ki,
    const float* __restrict__ vr, const float* __restrict__ vi,
    float* __restrict__ o_r, float* __restrict__ o_i)
{
    __shared__ float sQ[64][129];  // [m][d], d 0..63 = real, 64..127 = imag
    __shared__ float sK[32][65];   // one half (r or i) of K tile, [s][d]
    __shared__ float sP[64][33];   // softmaxed probs tile [m][s]
    __shared__ float sV[32][65];   // V tile (r then i), [s][d]

    const int t  = threadIdx.x;
    const int tx = t & 15;
    const int ty = t >> 4;

    const int bid  = blockIdx.x;
    const int mblk = bid & 31;         // L/64 = 32 tiles
    const int h    = (bid >> 5) & 15;
    const int b    = bid >> 9;

    const size_t qbase = ((size_t)b * LQ + (size_t)mblk * 64) * CH + (size_t)h * HD;
    const size_t kbase = ((size_t)b * SK) * CH + (size_t)h * HD;

    // Load Q tile (64x64 per half, coalesced 64-wide rows)
    #pragma unroll
    for (int rep = 0; rep < 16; rep++) {
        int idx = rep * 256 + t;
        int r = idx >> 6, c = idx & 63;
        size_t g = qbase + (size_t)r * CH + c;
        sQ[r][c]      = qr[g];
        sQ[r][64 + c] = qi[g];
    }

    float m_st[4], l_st[4];
    float oar[4][4] = {};
    float oai[4][4] = {};
    #pragma unroll
    for (int i = 0; i < 4; i++) { m_st[i] = -1e30f; l_st[i] = 0.f; }

    __syncthreads();

    for (int s0 = 0; s0 < SK; s0 += 32) {
        // ---- scores: sc[i][j] for rows ty*4+i, cols tx*2+j ----
        float sc[4][2] = {};
        #pragma unroll
        for (int part = 0; part < 2; part++) {
            const float* kp = part ? ki : kr;
            #pragma unroll
            for (int rep = 0; rep < 8; rep++) {
                int idx = rep * 256 + t;
                int r = idx >> 6, c = idx & 63;
                sK[r][c] = kp[kbase + (size_t)(s0 + r) * CH + c];
            }
            __syncthreads();
            #pragma unroll
            for (int kk = 0; kk < 64; kk++) {
                float a[4], bb[2];
                #pragma unroll
                for (int i = 0; i < 4; i++) a[i] = sQ[ty * 4 + i][part * 64 + kk];
                #pragma unroll
                for (int j = 0; j < 2; j++) bb[j] = sK[tx * 2 + j][kk];
                #pragma unroll
                for (int i = 0; i < 4; i++)
                    #pragma unroll
                    for (int j = 0; j < 2; j++)
                        sc[i][j] += a[i] * bb[j];
            }
            __syncthreads();
        }

        // ---- online softmax update (per row) ----
        float alpha[4];
        #pragma unroll
        for (int i = 0; i < 4; i++) {
            sc[i][0] *= ATT_SCALE;
            sc[i][1] *= ATT_SCALE;
            float rm = fmaxf(sc[i][0], sc[i][1]);
            #pragma unroll
            for (int off = 1; off < 16; off <<= 1)
                rm = fmaxf(rm, __shfl_xor(rm, off));
            float m_new = fmaxf(m_st[i], rm);
            alpha[i] = __expf(m_st[i] - m_new);
            float psum = 0.f;
            #pragma unroll
            for (int j = 0; j < 2; j++) {
                float p = __expf(sc[i][j] - m_new);
                sc[i][j] = p;
                psum += p;
            }
            #pragma unroll
            for (int off = 1; off < 16; off <<= 1)
                psum += __shfl_xor(psum, off);
            l_st[i] = l_st[i] * alpha[i] + psum;
            m_st[i] = m_new;
        }

        // stash P, rescale O accumulators
        #pragma unroll
        for (int i = 0; i < 4; i++)
            #pragma unroll
            for (int j = 0; j < 2; j++)
                sP[ty * 4 + i][tx * 2 + j] = sc[i][j];
        #pragma unroll
        for (int i = 0; i < 4; i++)
            #pragma unroll
            for (int j = 0; j < 4; j++) {
                oar[i][j] *= alpha[i];
                oai[i][j] *= alpha[i];
            }

        // ---- PV, real part ----
        #pragma unroll
        for (int rep = 0; rep < 8; rep++) {
            int idx = rep * 256 + t;
            int r = idx >> 6, c = idx & 63;
            sV[r][c] = vr[kbase + (size_t)(s0 + r) * CH + c];
        }
        __syncthreads();
        #pragma unroll
        for (int s = 0; s < 32; s++) {
            float pv[4], vv[4];
            #pragma unroll
            for (int i = 0; i < 4; i++) pv[i] = sP[ty * 4 + i][s];
            #pragma unroll
            for (int j = 0; j < 4; j++) vv[j] = sV[s][tx * 4 + j];
            #pragma unroll
            for (int i = 0; i < 4; i++)
                #pragma unroll
                for (int j = 0; j < 4; j++)
                    oar[i][j] += pv[i] * vv[j];
        }
        __syncthreads();

        // ---- PV, imag part ----
        #pragma unroll
        for (int rep = 0; rep < 8; rep++) {
            int idx = rep * 256 + t;
            int r = idx >> 6, c = idx & 63;
            sV[r][c] = vi[kbase + (size_t)(s0 + r) * CH + c];
        }
        __syncthreads();
        #pragma unroll
        for (int s = 0; s < 32; s++) {
            float pv[4], vv[4];
            #pragma unroll
            for (int i = 0; i < 4; i++) pv[i] = sP[ty * 4 + i][s];
            #pragma unroll
            for (int j = 0; j < 4; j++) vv[j] = sV[s][tx * 4 + j];
            #pragma unroll
            for (int i = 0; i < 4; i++)
                #pragma unroll
                for (int j = 0; j < 4; j++)
                    oai[i][j] += pv[i] * vv[j];
        }
        __syncthreads();
    }

    // ---- epilogue: normalize and write (aliases q buffers; safe per-block) ----
    #pragma unroll
    for (int i = 0; i < 4; i++) {
        float inv = 1.f / l_st[i];
        size_t obase = qbase + (size_t)(ty * 4 + i) * CH;
        #pragma unroll
        for (int j = 0; j < 4; j++) {
            o_r[obase + tx * 4 + j] = oar[i][j] * inv;
            o_i[obase + tx * 4 + j] = oai[i][j] * inv;
        }
    }
}

// ---------------------------------------------------------------------------
extern "C" void kernel_launch(void* const* d_in, const int* in_sizes, int n_in,
                              void* d_out, int out_size, void* d_ws, size_t ws_size,
                              hipStream_t stream)
{
    const float* in_r = (const float*)d_in[0];
    const float* in_i = (const float*)d_in[1];
    const float* cx_r = (const float*)d_in[2];
    const float* cx_i = (const float*)d_in[3];
    const float* wq_r = (const float*)d_in[4];
    const float* wq_i = (const float*)d_in[5];
    const float* wk_r = (const float*)d_in[6];
    const float* wk_i = (const float*)d_in[7];
    const float* wv_r = (const float*)d_in[8];
    const float* wv_i = (const float*)d_in[9];
    const float* wo_r = (const float*)d_in[10];
    const float* wo_i = (const float*)d_in[11];
    const float* bo_r = (const float*)d_in[12];
    const float* bo_i = (const float*)d_in[13];

    float* ws = (float*)d_ws;
    const size_t NB = (size_t)BB * LQ * CH;   // 4,194,304 elements per buffer
    float* qr = ws + 0 * NB;
    float* qi = ws + 1 * NB;
    float* kr = ws + 2 * NB;
    float* ki = ws + 3 * NB;
    float* vr = ws + 4 * NB;
    float* vi = ws + 5 * NB;
    // attention output aliases q buffers (each block reads only its own q rows
    // into LDS before writing the same rows) -> total ws use = 6*NB*4 = 100.7 MB
    float* o_r = qr;
    float* o_i = qi;

    float* out = (float*)d_out;
    float* yr = out;           // [0] real  (B,L,C)
    float* yi = out + NB;      // [1] imag  (B,L,C)

    const int M = BB * LQ;     // 4096
    dim3 gblk(CH / 64, M / 64);   // (16, 64)

    cgemm_kernel<false><<<gblk, 256, 0, stream>>>(in_r, in_i, wq_r, wq_i, qr, qi,
                                                  nullptr, nullptr, M, CH, CH);
    cgemm_kernel<false><<<gblk, 256, 0, stream>>>(cx_r, cx_i, wk_r, wk_i, kr, ki,
                                                  nullptr, nullptr, M, CH, CH);
    cgemm_kernel<false><<<gblk, 256, 0, stream>>>(cx_r, cx_i, wv_r, wv_i, vr, vi,
                                                  nullptr, nullptr, M, CH, CH);

    attn_kernel<<<dim3(BB * NH * (LQ / 64)), 256, 0, stream>>>(qr, qi, kr, ki,
                                                               vr, vi, o_r, o_i);

    cgemm_kernel<true><<<gblk, 256, 0, stream>>>(o_r, o_i, wo_r, wo_i, yr, yi,
                                                 bo_r, bo_i, M, CH, CH);
}

// Round 2
// 2560.330 us; speedup vs baseline: 3.2517x; 3.2517x over previous
//
#include <hip/hip_runtime.h>

// Problem constants (fixed by reference setup_inputs)
#define BB 2
#define LQ 2048
#define SK 2048
#define CH 1024
#define NH 16
#define HD 64
#define GK 2048          // packed complex K = 2*CH/ ... (=2048)
#define MM 4096          // B*L = B*S
#define ATT_SCALE 0.125f // 1/sqrt(64)

typedef __bf16 bf16x8 __attribute__((ext_vector_type(8)));
typedef float f32x4 __attribute__((ext_vector_type(4)));

__device__ __forceinline__ unsigned short f2bf(float f) {
    union { float f; unsigned int u; } v; v.f = f;
    unsigned int r = (v.u + 0x7fffu + ((v.u >> 16) & 1u)) >> 16;
    return (unsigned short)r;
}
__device__ __forceinline__ float bf2f(unsigned short u) {
    union { unsigned int u; float f; } v; v.u = ((unsigned int)u) << 16;
    return v.f;
}
__device__ __forceinline__ void gload16(const unsigned short* g, unsigned short* l) {
    __builtin_amdgcn_global_load_lds(
        (const __attribute__((address_space(1))) void*)g,
        (__attribute__((address_space(3))) void*)l, 16, 0, 0);
}

// ---------------------------------------------------------------------------
// pack_x: build packed A = [x_r | x_i]  (M, 2048) bf16, row-major.
// z=0: inputs -> Ain ; z=1: context -> Actx
// ---------------------------------------------------------------------------
struct PackXEnt { const float* r; const float* i; unsigned short* dst; };
struct PackXBatch { PackXEnt e[2]; };

__global__ __launch_bounds__(256) void pack_x_kernel(PackXBatch b)
{
    PackXEnt e = b.e[blockIdx.z];
    const size_t total = (size_t)MM * GK;
    for (size_t idx = (size_t)blockIdx.x * 256 + threadIdx.x; idx < total;
         idx += (size_t)gridDim.x * 256) {
        size_t m = idx >> 11;        // /2048
        int c = (int)(idx & 2047);
        float v = (c < CH) ? e.r[m * CH + c] : e.i[m * CH + (c - CH)];
        e.dst[idx] = f2bf(v);
    }
}

// ---------------------------------------------------------------------------
// pack_w: build Bt (N=1024, K=2048) bf16 = transposed packed weights.
//   part r: Bt[n][k] = k<1024 ?  wr[k][n] : -wi[k-1024][n]
//   part i: Bt[n][k] = k<1024 ?  wi[k][n] :  wr[k-1024][n]
// ---------------------------------------------------------------------------
struct PackWEnt { const float* a; const float* b; float signb; unsigned short* dst; };
struct PackWBatch { PackWEnt e[8]; };

__global__ __launch_bounds__(256) void pack_w_kernel(PackWBatch bt)
{
    PackWEnt e = bt.e[blockIdx.z];
    const int k0 = blockIdx.x * 32;
    const int n0 = blockIdx.y * 32;
    const float* src = (k0 < CH) ? e.a : e.b;
    const float sign = (k0 < CH) ? 1.f : e.signb;
    const int kk = k0 & (CH - 1);

    __shared__ float sT[32][33];
    const int t = threadIdx.x;
    const int tx = t & 31, ty = t >> 5;

    #pragma unroll
    for (int r = 0; r < 4; r++) {
        int kl = ty + r * 8;
        sT[kl][tx] = src[(size_t)(kk + kl) * CH + n0 + tx] * sign;
    }
    __syncthreads();
    #pragma unroll
    for (int r = 0; r < 4; r++) {
        int nl = ty + r * 8;
        e.dst[(size_t)(n0 + nl) * GK + k0 + tx] = f2bf(sT[tx][nl]);
    }
}

// ---------------------------------------------------------------------------
// bf16 MFMA GEMM (m97-style): C(M,1024) = A(M,2048) @ Bt(1024,2048)^T
// 128x128 tile, BK=32, 256 threads = 4 waves (2x2), each wave 64x64 via
// 4x4 grid of 16x16x32 mfma. global_load_lds width=16 staging for A and B.
// ---------------------------------------------------------------------------
struct GemmEnt { const unsigned short* A; const unsigned short* Bt; void* out; const float* bias; };
struct GemmBatch { GemmEnt e[6]; };

template <bool STORE_BF16>
__global__ __launch_bounds__(256) void mfma_cgemm(GemmBatch bt)
{
    GemmEnt e = bt.e[blockIdx.z];
    __shared__ unsigned short sA[128 * 32];
    __shared__ unsigned short sB[128 * 32];

    const int t = threadIdx.x;
    const int wave = t >> 6;
    const int lane = t & 63;
    const int wm = (wave >> 1) * 64;
    const int wn = (wave & 1) * 64;
    const int lm = lane & 15;
    const int quad = lane >> 4;

    const int m0 = blockIdx.y * 128;
    const int n0 = blockIdx.x * 128;

    // staging addresses: thread t handles 16B at row t>>2, seg (t&3)*8
    const int srow = t >> 2;
    const int sseg = (t & 3) * 8;
    const unsigned short* ga = e.A + (size_t)(m0 + srow) * GK + sseg;
    const unsigned short* gb = e.Bt + (size_t)(n0 + srow) * GK + sseg;
    unsigned short* la = sA + t * 8;
    unsigned short* lb = sB + t * 8;

    f32x4 acc[4][4] = {};

    for (int k0 = 0; k0 < GK; k0 += 32) {
        gload16(ga + k0, la);
        gload16(ga + k0 + (size_t)64 * GK, la + 64 * 32);
        gload16(gb + k0, lb);
        gload16(gb + k0 + (size_t)64 * GK, lb + 64 * 32);
        __syncthreads();

        bf16x8 af[4], bfr[4];
        #pragma unroll
        for (int i = 0; i < 4; i++)
            af[i] = *(const bf16x8*)&sA[(wm + i * 16 + lm) * 32 + quad * 8];
        #pragma unroll
        for (int j = 0; j < 4; j++)
            bfr[j] = *(const bf16x8*)&sB[(wn + j * 16 + lm) * 32 + quad * 8];
        #pragma unroll
        for (int i = 0; i < 4; i++)
            #pragma unroll
            for (int j = 0; j < 4; j++)
                acc[i][j] = __builtin_amdgcn_mfma_f32_16x16x32_bf16(
                    af[i], bfr[j], acc[i][j], 0, 0, 0);
        __syncthreads();
    }

    // epilogue: C row = quad*4+reg, col = lm within each 16x16 tile
    #pragma unroll
    for (int j = 0; j < 4; j++) {
        int gcol = n0 + wn + j * 16 + lm;
        float bv = e.bias ? e.bias[gcol] : 0.f;
        #pragma unroll
        for (int i = 0; i < 4; i++) {
            int grow = m0 + wm + i * 16 + quad * 4;
            #pragma unroll
            for (int reg = 0; reg < 4; reg++) {
                float v = acc[i][j][reg] + bv;
                size_t off = (size_t)(grow + reg) * CH + gcol;
                if (STORE_BF16) ((unsigned short*)e.out)[off] = f2bf(v);
                else            ((float*)e.out)[off] = v;
            }
        }
    }
}

// ---------------------------------------------------------------------------
// Flash-style complex cross attention (fp32 math, bf16 q/k/v in, bf16 packed out).
// Output written directly into packed A-layout (M, 2048): real at col h*64+d,
// imag at 1024 + h*64 + d.
// ---------------------------------------------------------------------------
__global__ __launch_bounds__(256) void attn_kernel(
    const unsigned short* __restrict__ qr, const unsigned short* __restrict__ qi,
    const unsigned short* __restrict__ kr, const unsigned short* __restrict__ ki,
    const unsigned short* __restrict__ vr, const unsigned short* __restrict__ vi,
    unsigned short* __restrict__ aattn)
{
    __shared__ float sQ[64][129];
    __shared__ float sK[32][65];
    __shared__ float sP[64][33];
    __shared__ float sV[32][65];

    const int t  = threadIdx.x;
    const int tx = t & 15;
    const int ty = t >> 4;

    const int bid  = blockIdx.x;
    const int mblk = bid & 31;
    const int h    = (bid >> 5) & 15;
    const int b    = bid >> 9;

    const size_t qbase = ((size_t)b * LQ + (size_t)mblk * 64) * CH + (size_t)h * HD;
    const size_t kbase = ((size_t)b * SK) * CH + (size_t)h * HD;

    #pragma unroll
    for (int rep = 0; rep < 16; rep++) {
        int idx = rep * 256 + t;
        int r = idx >> 6, c = idx & 63;
        size_t g = qbase + (size_t)r * CH + c;
        sQ[r][c]      = bf2f(qr[g]);
        sQ[r][64 + c] = bf2f(qi[g]);
    }

    float m_st[4], l_st[4];
    float oar[4][4] = {};
    float oai[4][4] = {};
    #pragma unroll
    for (int i = 0; i < 4; i++) { m_st[i] = -1e30f; l_st[i] = 0.f; }

    __syncthreads();

    for (int s0 = 0; s0 < SK; s0 += 32) {
        float sc[4][2] = {};
        #pragma unroll
        for (int part = 0; part < 2; part++) {
            const unsigned short* kp = part ? ki : kr;
            #pragma unroll
            for (int rep = 0; rep < 8; rep++) {
                int idx = rep * 256 + t;
                int r = idx >> 6, c = idx & 63;
                sK[r][c] = bf2f(kp[kbase + (size_t)(s0 + r) * CH + c]);
            }
            __syncthreads();
            #pragma unroll
            for (int kk = 0; kk < 64; kk++) {
                float a[4], bb[2];
                #pragma unroll
                for (int i = 0; i < 4; i++) a[i] = sQ[ty * 4 + i][part * 64 + kk];
                #pragma unroll
                for (int j = 0; j < 2; j++) bb[j] = sK[tx * 2 + j][kk];
                #pragma unroll
                for (int i = 0; i < 4; i++)
                    #pragma unroll
                    for (int j = 0; j < 2; j++)
                        sc[i][j] += a[i] * bb[j];
            }
            __syncthreads();
        }

        float alpha[4];
        #pragma unroll
        for (int i = 0; i < 4; i++) {
            sc[i][0] *= ATT_SCALE;
            sc[i][1] *= ATT_SCALE;
            float rm = fmaxf(sc[i][0], sc[i][1]);
            #pragma unroll
            for (int off = 1; off < 16; off <<= 1)
                rm = fmaxf(rm, __shfl_xor(rm, off));
            float m_new = fmaxf(m_st[i], rm);
            alpha[i] = __expf(m_st[i] - m_new);
            float psum = 0.f;
            #pragma unroll
            for (int j = 0; j < 2; j++) {
                float p = __expf(sc[i][j] - m_new);
                sc[i][j] = p;
                psum += p;
            }
            #pragma unroll
            for (int off = 1; off < 16; off <<= 1)
                psum += __shfl_xor(psum, off);
            l_st[i] = l_st[i] * alpha[i] + psum;
            m_st[i] = m_new;
        }

        #pragma unroll
        for (int i = 0; i < 4; i++)
            #pragma unroll
            for (int j = 0; j < 2; j++)
                sP[ty * 4 + i][tx * 2 + j] = sc[i][j];
        #pragma unroll
        for (int i = 0; i < 4; i++)
            #pragma unroll
            for (int j = 0; j < 4; j++) {
                oar[i][j] *= alpha[i];
                oai[i][j] *= alpha[i];
            }

        #pragma unroll
        for (int rep = 0; rep < 8; rep++) {
            int idx = rep * 256 + t;
            int r = idx >> 6, c = idx & 63;
            sV[r][c] = bf2f(vr[kbase + (size_t)(s0 + r) * CH + c]);
        }
        __syncthreads();
        #pragma unroll
        for (int s = 0; s < 32; s++) {
            float pv[4], vv[4];
            #pragma unroll
            for (int i = 0; i < 4; i++) pv[i] = sP[ty * 4 + i][s];
            #pragma unroll
            for (int j = 0; j < 4; j++) vv[j] = sV[s][tx * 4 + j];
            #pragma unroll
            for (int i = 0; i < 4; i++)
                #pragma unroll
                for (int j = 0; j < 4; j++)
                    oar[i][j] += pv[i] * vv[j];
        }
        __syncthreads();

        #pragma unroll
        for (int rep = 0; rep < 8; rep++) {
            int idx = rep * 256 + t;
            int r = idx >> 6, c = idx & 63;
            sV[r][c] = bf2f(vi[kbase + (size_t)(s0 + r) * CH + c]);
        }
        __syncthreads();
        #pragma unroll
        for (int s = 0; s < 32; s++) {
            float pv[4], vv[4];
            #pragma unroll
            for (int i = 0; i < 4; i++) pv[i] = sP[ty * 4 + i][s];
            #pragma unroll
            for (int j = 0; j < 4; j++) vv[j] = sV[s][tx * 4 + j];
            #pragma unroll
            for (int i = 0; i < 4; i++)
                #pragma unroll
                for (int j = 0; j < 4; j++)
                    oai[i][j] += pv[i] * vv[j];
        }
        __syncthreads();
    }

    // epilogue: normalize, write packed bf16 [o_r | o_i] (M, 2048)
    const size_t abase = ((size_t)b * LQ + (size_t)mblk * 64) * GK + (size_t)h * HD;
    #pragma unroll
    for (int i = 0; i < 4; i++) {
        float inv = 1.f / l_st[i];
        size_t ob = abase + (size_t)(ty * 4 + i) * GK;
        #pragma unroll
        for (int j = 0; j < 4; j++) {
            aattn[ob + tx * 4 + j]        = f2bf(oar[i][j] * inv);
            aattn[ob + CH + tx * 4 + j]   = f2bf(oai[i][j] * inv);
        }
    }
}

// ---------------------------------------------------------------------------
extern "C" void kernel_launch(void* const* d_in, const int* in_sizes, int n_in,
                              void* d_out, int out_size, void* d_ws, size_t ws_size,
                              hipStream_t stream)
{
    const float* in_r = (const float*)d_in[0];
    const float* in_i = (const float*)d_in[1];
    const float* cx_r = (const float*)d_in[2];
    const float* cx_i = (const float*)d_in[3];
    const float* wq_r = (const float*)d_in[4];
    const float* wq_i = (const float*)d_in[5];
    const float* wk_r = (const float*)d_in[6];
    const float* wk_i = (const float*)d_in[7];
    const float* wv_r = (const float*)d_in[8];
    const float* wv_i = (const float*)d_in[9];
    const float* wo_r = (const float*)d_in[10];
    const float* wo_i = (const float*)d_in[11];
    const float* bo_r = (const float*)d_in[12];
    const float* bo_i = (const float*)d_in[13];

    // workspace layout (bytes):
    //  Ain/Aattn : 4096*2048*2 = 16 MiB   (Aattn aliases Ain; Ain dead after qkv GEMM)
    //  Actx      : 16 MiB
    //  Bpacks[8] : 8 * 4 MiB = 32 MiB
    //  qkv bf16  : 6 * 8 MiB = 48 MiB
    unsigned short* ws = (unsigned short*)d_ws;
    const size_t A_ELEMS = (size_t)MM * GK;       // 8,388,608
    const size_t B_ELEMS = (size_t)CH * GK;       // 2,097,152
    const size_t Q_ELEMS = (size_t)MM * CH;       // 4,194,304

    unsigned short* Ain   = ws;
    unsigned short* Aattn = ws;                   // alias (safe: Ain dead first)
    unsigned short* Actx  = Ain + A_ELEMS;
    unsigned short* Bp    = Actx + A_ELEMS;       // 8 consecutive packs
    unsigned short* Qkv   = Bp + 8 * B_ELEMS;     // 6 consecutive buffers

    unsigned short* Bq_r = Bp + 0 * B_ELEMS;
    unsigned short* Bq_i = Bp + 1 * B_ELEMS;
    unsigned short* Bk_r = Bp + 2 * B_ELEMS;
    unsigned short* Bk_i = Bp + 3 * B_ELEMS;
    unsigned short* Bv_r = Bp + 4 * B_ELEMS;
    unsigned short* Bv_i = Bp + 5 * B_ELEMS;
    unsigned short* Bo_r = Bp + 6 * B_ELEMS;
    unsigned short* Bo_i = Bp + 7 * B_ELEMS;

    unsigned short* q_r = Qkv + 0 * Q_ELEMS;
    unsigned short* q_i = Qkv + 1 * Q_ELEMS;
    unsigned short* k_r = Qkv + 2 * Q_ELEMS;
    unsigned short* k_i = Qkv + 3 * Q_ELEMS;
    unsigned short* v_r = Qkv + 4 * Q_ELEMS;
    unsigned short* v_i = Qkv + 5 * Q_ELEMS;

    float* out = (float*)d_out;
    float* yr = out;
    float* yi = out + (size_t)MM * CH;

    // ---- pack inputs ----
    PackXBatch px;
    px.e[0] = { in_r, in_i, Ain  };
    px.e[1] = { cx_r, cx_i, Actx };
    pack_x_kernel<<<dim3(4096, 1, 2), 256, 0, stream>>>(px);

    PackWBatch pw;
    pw.e[0] = { wq_r, wq_i, -1.f, Bq_r };
    pw.e[1] = { wq_i, wq_r,  1.f, Bq_i };
    pw.e[2] = { wk_r, wk_i, -1.f, Bk_r };
    pw.e[3] = { wk_i, wk_r,  1.f, Bk_i };
    pw.e[4] = { wv_r, wv_i, -1.f, Bv_r };
    pw.e[5] = { wv_i, wv_r,  1.f, Bv_i };
    pw.e[6] = { wo_r, wo_i, -1.f, Bo_r };
    pw.e[7] = { wo_i, wo_r,  1.f, Bo_i };
    pack_w_kernel<<<dim3(GK / 32, CH / 32, 8), 256, 0, stream>>>(pw);

    // ---- q,k,v projections (6 GEMMs in one launch) ----
    GemmBatch gq;
    gq.e[0] = { Ain,  Bq_r, q_r, nullptr };
    gq.e[1] = { Ain,  Bq_i, q_i, nullptr };
    gq.e[2] = { Actx, Bk_r, k_r, nullptr };
    gq.e[3] = { Actx, Bk_i, k_i, nullptr };
    gq.e[4] = { Actx, Bv_r, v_r, nullptr };
    gq.e[5] = { Actx, Bv_i, v_i, nullptr };
    mfma_cgemm<true><<<dim3(CH / 128, MM / 128, 6), 256, 0, stream>>>(gq);

    // ---- attention ----
    attn_kernel<<<dim3(BB * NH * (LQ / 64)), 256, 0, stream>>>(
        q_r, q_i, k_r, k_i, v_r, v_i, Aattn);

    // ---- output projection (+bias) ----
    GemmBatch go;
    go.e[0] = { Aattn, Bo_r, yr, bo_r };
    go.e[1] = { Aattn, Bo_i, yi, bo_i };
    for (int z = 2; z < 6; z++) go.e[z] = go.e[0];
    mfma_cgemm<false><<<dim3(CH / 128, MM / 128, 2), 256, 0, stream>>>(go);
}

// Round 3
// 590.856 us; speedup vs baseline: 14.0906x; 4.3333x over previous
//
#include <hip/hip_runtime.h>

// Problem constants (fixed by reference setup_inputs)
#define BB 2
#define LQ 2048
#define SK 2048
#define CH 1024
#define NH 16
#define HD 64
#define GK 2048          // packed complex K (= 2*CH)
#define MM 4096          // B*L = B*S
#define ATT_SCALE 0.125f // 1/sqrt(64)

typedef _Float16 f16x8 __attribute__((ext_vector_type(8)));
typedef float f32x4 __attribute__((ext_vector_type(4)));
typedef unsigned short u16x8 __attribute__((ext_vector_type(8)));

__device__ __forceinline__ unsigned short h2u(_Float16 h) {
    union { _Float16 h; unsigned short u; } v; v.h = h; return v.u;
}
__device__ __forceinline__ void gload16(const _Float16* g, unsigned short* l) {
    __builtin_amdgcn_global_load_lds(
        (const __attribute__((address_space(1))) void*)g,
        (__attribute__((address_space(3))) void*)l, 16, 0, 0);
}

// ---------------------------------------------------------------------------
// pack_x: build packed A = [x_r | x_i]  (M, 2048) fp16, row-major.
// ---------------------------------------------------------------------------
struct PackXEnt { const float* r; const float* i; _Float16* dst; };
struct PackXBatch { PackXEnt e[2]; };

__global__ __launch_bounds__(256) void pack_x_kernel(PackXBatch b)
{
    PackXEnt e = b.e[blockIdx.z];
    const size_t total = (size_t)MM * GK;
    for (size_t idx = (size_t)blockIdx.x * 256 + threadIdx.x; idx < total;
         idx += (size_t)gridDim.x * 256) {
        size_t m = idx >> 11;
        int c = (int)(idx & 2047);
        float v = (c < CH) ? e.r[m * CH + c] : e.i[m * CH + (c - CH)];
        e.dst[idx] = (_Float16)v;
    }
}

// ---------------------------------------------------------------------------
// pack_w: Bt (N=1024, K=2048) fp16 = transposed packed weights.
//   part r: Bt[n][k] = k<1024 ?  wr[k][n] : -wi[k-1024][n]
//   part i: Bt[n][k] = k<1024 ?  wi[k][n] :  wr[k-1024][n]
// ---------------------------------------------------------------------------
struct PackWEnt { const float* a; const float* b; float signb; _Float16* dst; };
struct PackWBatch { PackWEnt e[8]; };

__global__ __launch_bounds__(256) void pack_w_kernel(PackWBatch bt)
{
    PackWEnt e = bt.e[blockIdx.z];
    const int k0 = blockIdx.x * 32;
    const int n0 = blockIdx.y * 32;
    const float* src = (k0 < CH) ? e.a : e.b;
    const float sign = (k0 < CH) ? 1.f : e.signb;
    const int kk = k0 & (CH - 1);

    __shared__ float sT[32][33];
    const int t = threadIdx.x;
    const int tx = t & 31, ty = t >> 5;

    #pragma unroll
    for (int r = 0; r < 4; r++) {
        int kl = ty + r * 8;
        sT[kl][tx] = src[(size_t)(kk + kl) * CH + n0 + tx] * sign;
    }
    __syncthreads();
    #pragma unroll
    for (int r = 0; r < 4; r++) {
        int nl = ty + r * 8;
        e.dst[(size_t)(n0 + nl) * GK + k0 + tx] = (_Float16)sT[tx][nl];
    }
}

// ---------------------------------------------------------------------------
// fp16 MFMA GEMM: C(M,1024) = A(M,2048) @ Bt(1024,2048)^T
// 128x128 tile, BK=32, 256 threads, m97-style global_load_lds staging.
// Epilogue modes: 0 = head-packed QK fp16 [b][h][l][128] (+part*64)
//                 1 = head-packed V^T fp16 [b][h][d][s]
//                 2 = fp32 + bias (final output)
// ---------------------------------------------------------------------------
struct GemmEnt { const _Float16* A; const _Float16* Bt; void* out;
                 const float* bias; int mode; int part; };
struct GemmBatch { GemmEnt e[6]; };

__global__ __launch_bounds__(256) void mfma_cgemm(GemmBatch bt)
{
    GemmEnt e = bt.e[blockIdx.z];
    __shared__ unsigned short sA[128 * 32];
    __shared__ unsigned short sB[128 * 32];

    const int t = threadIdx.x;
    const int wave = t >> 6;
    const int lane = t & 63;
    const int wm = (wave >> 1) * 64;
    const int wn = (wave & 1) * 64;
    const int lm = lane & 15;
    const int quad = lane >> 4;

    const int m0 = blockIdx.y * 128;
    const int n0 = blockIdx.x * 128;

    const int srow = t >> 2;
    const int sseg = (t & 3) * 8;
    const _Float16* ga = e.A + (size_t)(m0 + srow) * GK + sseg;
    const _Float16* gb = e.Bt + (size_t)(n0 + srow) * GK + sseg;
    unsigned short* la = sA + t * 8;
    unsigned short* lb = sB + t * 8;

    f32x4 acc[4][4] = {};

    for (int k0 = 0; k0 < GK; k0 += 32) {
        gload16(ga + k0, la);
        gload16(ga + k0 + (size_t)64 * GK, la + 64 * 32);
        gload16(gb + k0, lb);
        gload16(gb + k0 + (size_t)64 * GK, lb + 64 * 32);
        __syncthreads();

        f16x8 af[4], bfr[4];
        #pragma unroll
        for (int i = 0; i < 4; i++)
            af[i] = *(const f16x8*)&sA[(wm + i * 16 + lm) * 32 + quad * 8];
        #pragma unroll
        for (int j = 0; j < 4; j++)
            bfr[j] = *(const f16x8*)&sB[(wn + j * 16 + lm) * 32 + quad * 8];
        #pragma unroll
        for (int i = 0; i < 4; i++)
            #pragma unroll
            for (int j = 0; j < 4; j++)
                acc[i][j] = __builtin_amdgcn_mfma_f32_16x16x32_f16(
                    af[i], bfr[j], acc[i][j], 0, 0, 0);
        __syncthreads();
    }

    const int mode = e.mode, part = e.part;
    #pragma unroll
    for (int j = 0; j < 4; j++) {
        int gcol = n0 + wn + j * 16 + lm;
        float bv = (mode == 2 && e.bias) ? e.bias[gcol] : 0.f;
        #pragma unroll
        for (int i = 0; i < 4; i++) {
            int growb = m0 + wm + i * 16 + quad * 4;
            #pragma unroll
            for (int reg = 0; reg < 4; reg++) {
                int grow = growb + reg;
                float v = acc[i][j][reg];
                if (mode == 2) {
                    ((float*)e.out)[(size_t)grow * CH + gcol] = v + bv;
                } else {
                    int b = grow >> 11, l = grow & 2047;
                    int h = gcol >> 6, dd = gcol & 63;
                    size_t off;
                    if (mode == 0)
                        off = (((size_t)(b * NH + h)) * LQ + l) * 128 + part * 64 + dd;
                    else
                        off = (((size_t)(b * NH + h)) * 128 + part * 64 + dd) * SK + l;
                    ((_Float16*)e.out)[off] = (_Float16)v;
                }
            }
        }
    }
}

// ---------------------------------------------------------------------------
// MFMA flash attention.
// Block: 128 Q-rows of one (b,h). 256 threads = 4 waves; wave w owns rows
// [w*32, w*32+32). S iterated in 64-chunks, K/V software-pipelined via VGPRs.
// QK^T and PV are 16x16x32 fp16 MFMA; softmax fp32 on C-layout (row =
// quad*4+reg, col = lm -> width-16 shfl reductions). P -> LDS (wave-local,
// no barrier) to convert C-layout to A-operand layout for PV.
// LDS strides 136/72 elems: 16B-aligned and bank-uniform for ds_*_b128.
// ---------------------------------------------------------------------------
#define ATSQ 136
#define ATSV 72

__global__ __launch_bounds__(256, 1) void attn_mfma(
    const _Float16* __restrict__ Qp, const _Float16* __restrict__ Kp,
    const _Float16* __restrict__ Vt, _Float16* __restrict__ Aattn)
{
    __shared__ unsigned short lds[44544];
    unsigned short* sQ = lds;            // 128 x 136
    unsigned short* sK = lds + 17408;    // 64 x 136
    unsigned short* sV = lds + 26112;    // 128 x 72 (V^T: rows d, cols s)
    unsigned short* sP = lds + 35328;    // 128 x 72

    const int t    = threadIdx.x;
    const int w    = t >> 6;
    const int lane = t & 63;
    const int lm   = lane & 15;
    const int quad = lane >> 4;

    const int bid = blockIdx.x;
    const int mt  = bid & 15;
    const int h   = (bid >> 4) & 15;
    const int b   = bid >> 8;

    const _Float16* qb = Qp + (((size_t)(b * NH + h)) * LQ + (size_t)mt * 128) * 128;
    const _Float16* kb = Kp + ((size_t)(b * NH + h)) * SK * 128;
    const _Float16* vb = Vt + ((size_t)(b * NH + h)) * 128 * SK;

    // stage Q tile (128 x 128)
    #pragma unroll
    for (int p = 0; p < 8; p++) {
        int idx = p * 256 + t;
        int r = idx >> 4, sg = idx & 15;
        u16x8 x = *(const u16x8*)(qb + (size_t)r * 128 + sg * 8);
        *(u16x8*)&sQ[r * ATSQ + sg * 8] = x;
    }

    // preload K/V tile 0 into regs
    u16x8 kreg[4], vreg[4];
    #pragma unroll
    for (int p = 0; p < 4; p++) {
        int idx = p * 256 + t;
        int r = idx >> 4, sg = idx & 15;
        kreg[p] = *(const u16x8*)(kb + (size_t)r * 128 + sg * 8);
        int rv = idx >> 3, sv = idx & 7;
        vreg[p] = *(const u16x8*)(vb + (size_t)rv * SK + sv * 8);
    }

    f32x4 oacc[2][8] = {};
    float m_st[2][4], l_st[2][4];
    #pragma unroll
    for (int i = 0; i < 2; i++)
        #pragma unroll
        for (int r = 0; r < 4; r++) { m_st[i][r] = -1e30f; l_st[i][r] = 0.f; }

    const float SC2 = ATT_SCALE * 1.44269504f;   // exp2 domain

    for (int it = 0; it < SK / 64; ++it) {
        if (it) __syncthreads();                 // prior-iter sK/sV reads done
        #pragma unroll
        for (int p = 0; p < 4; p++) {
            int idx = p * 256 + t;
            int r = idx >> 4, sg = idx & 15;
            *(u16x8*)&sK[r * ATSQ + sg * 8] = kreg[p];
            int rv = idx >> 3, sv = idx & 7;
            *(u16x8*)&sV[rv * ATSV + sv * 8] = vreg[p];
        }
        __syncthreads();

        if (it + 1 < SK / 64) {                  // prefetch next tile
            int s0n = (it + 1) * 64;
            #pragma unroll
            for (int p = 0; p < 4; p++) {
                int idx = p * 256 + t;
                int r = idx >> 4, sg = idx & 15;
                kreg[p] = *(const u16x8*)(kb + (size_t)(s0n + r) * 128 + sg * 8);
                int rv = idx >> 3, sv = idx & 7;
                vreg[p] = *(const u16x8*)(vb + (size_t)rv * SK + s0n + sv * 8);
            }
        }

        // ---- QK^T: wave rows 32 x cols 64, k = 128 ----
        f32x4 sacc[2][4] = {};
        #pragma unroll
        for (int kk = 0; kk < 4; kk++) {
            f16x8 af[2], bfr[4];
            #pragma unroll
            for (int i = 0; i < 2; i++)
                af[i] = *(const f16x8*)&sQ[(w * 32 + i * 16 + lm) * ATSQ + kk * 32 + quad * 8];
            #pragma unroll
            for (int j = 0; j < 4; j++)
                bfr[j] = *(const f16x8*)&sK[(j * 16 + lm) * ATSQ + kk * 32 + quad * 8];
            #pragma unroll
            for (int i = 0; i < 2; i++)
                #pragma unroll
                for (int j = 0; j < 4; j++)
                    sacc[i][j] = __builtin_amdgcn_mfma_f32_16x16x32_f16(
                        af[i], bfr[j], sacc[i][j], 0, 0, 0);
        }

        // ---- online softmax (fp32, exp2 domain) ----
        #pragma unroll
        for (int i = 0; i < 2; i++) {
            #pragma unroll
            for (int r = 0; r < 4; r++) {
                float mx = fmaxf(fmaxf(sacc[0 + i * 0][0][0], sacc[i][0][r]), sacc[i][0][r]);
                mx = sacc[i][0][r];
                #pragma unroll
                for (int j = 1; j < 4; j++) mx = fmaxf(mx, sacc[i][j][r]);
                #pragma unroll
                for (int off = 1; off < 16; off <<= 1)
                    mx = fmaxf(mx, __shfl_xor(mx, off, 16));
                mx *= SC2;
                float mnew = fmaxf(m_st[i][r], mx);
                float al = exp2f(m_st[i][r] - mnew);
                float ps = 0.f;
                float pj[4];
                #pragma unroll
                for (int j = 0; j < 4; j++) {
                    pj[j] = exp2f(sacc[i][j][r] * SC2 - mnew);
                    ps += pj[j];
                }
                #pragma unroll
                for (int off = 1; off < 16; off <<= 1)
                    ps += __shfl_xor(ps, off, 16);
                l_st[i][r] = l_st[i][r] * al + ps;
                m_st[i][r] = mnew;
                int prow = (w * 32 + i * 16 + quad * 4 + r) * ATSV;
                #pragma unroll
                for (int j = 0; j < 4; j++)
                    sP[prow + j * 16 + lm] = h2u((_Float16)pj[j]);
                #pragma unroll
                for (int j2 = 0; j2 < 8; j2++)
                    oacc[i][j2][r] *= al;
            }
        }

        // ---- PV: O[m][d] += P[m][s] * Vt[d][s] ----
        #pragma unroll
        for (int kk = 0; kk < 2; kk++) {
            f16x8 pf[2], vf[8];
            #pragma unroll
            for (int i = 0; i < 2; i++)
                pf[i] = *(const f16x8*)&sP[(w * 32 + i * 16 + lm) * ATSV + kk * 32 + quad * 8];
            #pragma unroll
            for (int j2 = 0; j2 < 8; j2++)
                vf[j2] = *(const f16x8*)&sV[(j2 * 16 + lm) * ATSV + kk * 32 + quad * 8];
            #pragma unroll
            for (int i = 0; i < 2; i++)
                #pragma unroll
                for (int j2 = 0; j2 < 8; j2++)
                    oacc[i][j2] = __builtin_amdgcn_mfma_f32_16x16x32_f16(
                        pf[i], vf[j2], oacc[i][j2], 0, 0, 0);
        }
    }

    // ---- epilogue: normalize, write packed fp16 [o_r | o_i] (M, 2048) ----
    #pragma unroll
    for (int i = 0; i < 2; i++) {
        #pragma unroll
        for (int r = 0; r < 4; r++) {
            float inv = 1.f / l_st[i][r];
            int ml = w * 32 + i * 16 + quad * 4 + r;
            size_t row = (size_t)b * LQ + (size_t)mt * 128 + ml;
            #pragma unroll
            for (int j2 = 0; j2 < 8; j2++) {
                int d = j2 * 16 + lm;
                int dcol = (d < HD) ? h * HD + d : CH + h * HD + (d - HD);
                Aattn[row * GK + dcol] = (_Float16)(oacc[i][j2][r] * inv);
            }
        }
    }
}

// ---------------------------------------------------------------------------
extern "C" void kernel_launch(void* const* d_in, const int* in_sizes, int n_in,
                              void* d_out, int out_size, void* d_ws, size_t ws_size,
                              hipStream_t stream)
{
    const float* in_r = (const float*)d_in[0];
    const float* in_i = (const float*)d_in[1];
    const float* cx_r = (const float*)d_in[2];
    const float* cx_i = (const float*)d_in[3];
    const float* wq_r = (const float*)d_in[4];
    const float* wq_i = (const float*)d_in[5];
    const float* wk_r = (const float*)d_in[6];
    const float* wk_i = (const float*)d_in[7];
    const float* wv_r = (const float*)d_in[8];
    const float* wv_i = (const float*)d_in[9];
    const float* wo_r = (const float*)d_in[10];
    const float* wo_i = (const float*)d_in[11];
    const float* bo_r = (const float*)d_in[12];
    const float* bo_i = (const float*)d_in[13];

    _Float16* ws = (_Float16*)d_ws;
    const size_t A_ELEMS = (size_t)MM * GK;        // 8,388,608
    const size_t B_ELEMS = (size_t)CH * GK;        // 2,097,152
    const size_t H_ELEMS = (size_t)BB * NH * LQ * 128;  // 8,388,608

    _Float16* Ain   = ws;
    _Float16* Aattn = ws;                          // alias (Ain dead after qkv GEMM)
    _Float16* Actx  = Ain + A_ELEMS;
    _Float16* Bp    = Actx + A_ELEMS;
    _Float16* Qp    = Bp + 8 * B_ELEMS;
    _Float16* Kp    = Qp + H_ELEMS;
    _Float16* Vt    = Kp + H_ELEMS;
    // total ws: (2*8.39M + 8*2.1M + 3*8.39M)*2B ≈ 117 MB

    _Float16* Bq_r = Bp + 0 * B_ELEMS;
    _Float16* Bq_i = Bp + 1 * B_ELEMS;
    _Float16* Bk_r = Bp + 2 * B_ELEMS;
    _Float16* Bk_i = Bp + 3 * B_ELEMS;
    _Float16* Bv_r = Bp + 4 * B_ELEMS;
    _Float16* Bv_i = Bp + 5 * B_ELEMS;
    _Float16* Bo_r = Bp + 6 * B_ELEMS;
    _Float16* Bo_i = Bp + 7 * B_ELEMS;

    float* out = (float*)d_out;
    float* yr = out;
    float* yi = out + (size_t)MM * CH;

    PackXBatch px;
    px.e[0] = { in_r, in_i, Ain  };
    px.e[1] = { cx_r, cx_i, Actx };
    pack_x_kernel<<<dim3(4096, 1, 2), 256, 0, stream>>>(px);

    PackWBatch pw;
    pw.e[0] = { wq_r, wq_i, -1.f, Bq_r };
    pw.e[1] = { wq_i, wq_r,  1.f, Bq_i };
    pw.e[2] = { wk_r, wk_i, -1.f, Bk_r };
    pw.e[3] = { wk_i, wk_r,  1.f, Bk_i };
    pw.e[4] = { wv_r, wv_i, -1.f, Bv_r };
    pw.e[5] = { wv_i, wv_r,  1.f, Bv_i };
    pw.e[6] = { wo_r, wo_i, -1.f, Bo_r };
    pw.e[7] = { wo_i, wo_r,  1.f, Bo_i };
    pack_w_kernel<<<dim3(GK / 32, CH / 32, 8), 256, 0, stream>>>(pw);

    // q,k,v projections with head-packed epilogues
    GemmBatch gq;
    gq.e[0] = { Ain,  Bq_r, Qp, nullptr, 0, 0 };
    gq.e[1] = { Ain,  Bq_i, Qp, nullptr, 0, 1 };
    gq.e[2] = { Actx, Bk_r, Kp, nullptr, 0, 0 };
    gq.e[3] = { Actx, Bk_i, Kp, nullptr, 0, 1 };
    gq.e[4] = { Actx, Bv_r, Vt, nullptr, 1, 0 };
    gq.e[5] = { Actx, Bv_i, Vt, nullptr, 1, 1 };
    mfma_cgemm<<<dim3(CH / 128, MM / 128, 6), 256, 0, stream>>>(gq);

    attn_mfma<<<dim3(BB * NH * (LQ / 128)), 256, 0, stream>>>(Qp, Kp, Vt, Aattn);

    GemmBatch go;
    go.e[0] = { Aattn, Bo_r, yr, bo_r, 2, 0 };
    go.e[1] = { Aattn, Bo_i, yi, bo_i, 2, 1 };
    for (int z = 2; z < 6; z++) go.e[z] = go.e[0];
    mfma_cgemm<<<dim3(CH / 128, MM / 128, 2), 256, 0, stream>>>(go);
}

// Round 5
// 502.228 us; speedup vs baseline: 16.5772x; 1.1765x over previous
//
#include <hip/hip_runtime.h>

// Problem constants (fixed by reference setup_inputs)
#define BB 2
#define LQ 2048
#define SK 2048
#define CH 1024
#define NH 16
#define HD 64
#define GK 2048          // packed complex K (= 2*CH)
#define MM 4096          // B*L = B*S
#define ATT_SCALE 0.125f // 1/sqrt(64)

typedef _Float16 f16x8 __attribute__((ext_vector_type(8)));
typedef float f32x4 __attribute__((ext_vector_type(4)));
typedef unsigned short u16x8 __attribute__((ext_vector_type(8)));

__device__ __forceinline__ unsigned short h2u(_Float16 h) {
    union { _Float16 h; unsigned short u; } v; v.h = h; return v.u;
}
__device__ __forceinline__ void gload16(const _Float16* g, unsigned short* l) {
    __builtin_amdgcn_global_load_lds(
        (const __attribute__((address_space(1))) void*)g,
        (__attribute__((address_space(3))) void*)l, 16, 0, 0);
}

// 16-lane all-reduce max via DPP (full-rate VALU, no LDS pipe).
// Groups are lanes [quad*16, quad*16+15] -> aligned to DPP rows.
__device__ __forceinline__ float dpp_max16(float x) {
    union { float f; int i; } v, r;
    v.f = x;
    r.i = __builtin_amdgcn_update_dpp(v.i, v.i, 0xB1, 0xF, 0xF, false);  // quad_perm [1,0,3,2]
    v.f = fmaxf(v.f, r.f);
    r.i = __builtin_amdgcn_update_dpp(v.i, v.i, 0x4E, 0xF, 0xF, false);  // quad_perm [2,3,0,1]
    v.f = fmaxf(v.f, r.f);
    r.i = __builtin_amdgcn_update_dpp(v.i, v.i, 0x141, 0xF, 0xF, false); // row_half_mirror
    v.f = fmaxf(v.f, r.f);
    r.i = __builtin_amdgcn_update_dpp(v.i, v.i, 0x140, 0xF, 0xF, false); // row_mirror
    v.f = fmaxf(v.f, r.f);
    return v.f;
}

// ---------------------------------------------------------------------------
// pack_x: build packed A = [x_r | x_i]  (M, 2048) fp16, row-major.
// ---------------------------------------------------------------------------
struct PackXEnt { const float* r; const float* i; _Float16* dst; };
struct PackXBatch { PackXEnt e[2]; };

__global__ __launch_bounds__(256) void pack_x_kernel(PackXBatch b)
{
    PackXEnt e = b.e[blockIdx.z];
    const size_t total = (size_t)MM * GK;
    for (size_t idx = (size_t)blockIdx.x * 256 + threadIdx.x; idx < total;
         idx += (size_t)gridDim.x * 256) {
        size_t m = idx >> 11;
        int c = (int)(idx & 2047);
        float v = (c < CH) ? e.r[m * CH + c] : e.i[m * CH + (c - CH)];
        e.dst[idx] = (_Float16)v;
    }
}

// ---------------------------------------------------------------------------
// pack_w: Bt (N=1024, K=2048) fp16 = transposed packed weights.
// ---------------------------------------------------------------------------
struct PackWEnt { const float* a; const float* b; float signb; _Float16* dst; };
struct PackWBatch { PackWEnt e[8]; };

__global__ __launch_bounds__(256) void pack_w_kernel(PackWBatch bt)
{
    PackWEnt e = bt.e[blockIdx.z];
    const int k0 = blockIdx.x * 32;
    const int n0 = blockIdx.y * 32;
    const float* src = (k0 < CH) ? e.a : e.b;
    const float sign = (k0 < CH) ? 1.f : e.signb;
    const int kk = k0 & (CH - 1);

    __shared__ float sT[32][33];
    const int t = threadIdx.x;
    const int tx = t & 31, ty = t >> 5;

    #pragma unroll
    for (int r = 0; r < 4; r++) {
        int kl = ty + r * 8;
        sT[kl][tx] = src[(size_t)(kk + kl) * CH + n0 + tx] * sign;
    }
    __syncthreads();
    #pragma unroll
    for (int r = 0; r < 4; r++) {
        int nl = ty + r * 8;
        e.dst[(size_t)(n0 + nl) * GK + k0 + tx] = (_Float16)sT[tx][nl];
    }
}

// ---------------------------------------------------------------------------
// fp16 MFMA GEMM: C(M,1024) = A(M,2048) @ Bt(1024,2048)^T
// Epilogue modes: 0 = head-packed QK fp16 [b][h][l][128] (+part*64)
//                 1 = head-packed V^T fp16 [b][h][d][s]
//                 2 = fp32 + bias (final output)
// ---------------------------------------------------------------------------
struct GemmEnt { const _Float16* A; const _Float16* Bt; void* out;
                 const float* bias; int mode; int part; };
struct GemmBatch { GemmEnt e[6]; };

__global__ __launch_bounds__(256) void mfma_cgemm(GemmBatch bt)
{
    GemmEnt e = bt.e[blockIdx.z];
    __shared__ unsigned short sA[128 * 32];
    __shared__ unsigned short sB[128 * 32];

    const int t = threadIdx.x;
    const int wave = t >> 6;
    const int lane = t & 63;
    const int wm = (wave >> 1) * 64;
    const int wn = (wave & 1) * 64;
    const int lm = lane & 15;
    const int quad = lane >> 4;

    const int m0 = blockIdx.y * 128;
    const int n0 = blockIdx.x * 128;

    const int srow = t >> 2;
    const int sseg = (t & 3) * 8;
    const _Float16* ga = e.A + (size_t)(m0 + srow) * GK + sseg;
    const _Float16* gb = e.Bt + (size_t)(n0 + srow) * GK + sseg;
    unsigned short* la = sA + t * 8;
    unsigned short* lb = sB + t * 8;

    f32x4 acc[4][4] = {};

    for (int k0 = 0; k0 < GK; k0 += 32) {
        gload16(ga + k0, la);
        gload16(ga + k0 + (size_t)64 * GK, la + 64 * 32);
        gload16(gb + k0, lb);
        gload16(gb + k0 + (size_t)64 * GK, lb + 64 * 32);
        __syncthreads();

        f16x8 af[4], bfr[4];
        #pragma unroll
        for (int i = 0; i < 4; i++)
            af[i] = *(const f16x8*)&sA[(wm + i * 16 + lm) * 32 + quad * 8];
        #pragma unroll
        for (int j = 0; j < 4; j++)
            bfr[j] = *(const f16x8*)&sB[(wn + j * 16 + lm) * 32 + quad * 8];
        #pragma unroll
        for (int i = 0; i < 4; i++)
            #pragma unroll
            for (int j = 0; j < 4; j++)
                acc[i][j] = __builtin_amdgcn_mfma_f32_16x16x32_f16(
                    af[i], bfr[j], acc[i][j], 0, 0, 0);
        __syncthreads();
    }

    const int mode = e.mode, part = e.part;
    #pragma unroll
    for (int j = 0; j < 4; j++) {
        int gcol = n0 + wn + j * 16 + lm;
        float bv = (mode == 2 && e.bias) ? e.bias[gcol] : 0.f;
        #pragma unroll
        for (int i = 0; i < 4; i++) {
            int growb = m0 + wm + i * 16 + quad * 4;
            #pragma unroll
            for (int reg = 0; reg < 4; reg++) {
                int grow = growb + reg;
                float v = acc[i][j][reg];
                if (mode == 2) {
                    ((float*)e.out)[(size_t)grow * CH + gcol] = v + bv;
                } else {
                    int b = grow >> 11, l = grow & 2047;
                    int h = gcol >> 6, dd = gcol & 63;
                    size_t off;
                    if (mode == 0)
                        off = (((size_t)(b * NH + h)) * LQ + l) * 128 + part * 64 + dd;
                    else
                        off = (((size_t)(b * NH + h)) * 128 + part * 64 + dd) * SK + l;
                    ((_Float16*)e.out)[off] = (_Float16)v;
                }
            }
        }
    }
}

// ---------------------------------------------------------------------------
// MFMA flash attention (round 5 = round 4 + 2 bug fixes):
//  FIX 1: ALL 16 tail rows of V^T are ones -> every column 128..143 of the
//         9th accumulator tile equals sum(P) -> every lane (lm) holds its own
//         row's l. (Round 4 had ones in row 128 only -> l only in lm==0 lanes,
//         1/0 = inf -> NaN for lm!=0.)
//  FIX 2: unconditional __syncthreads() at K-loop top: protects cross-wave
//         qf reads from the it=0 sK writes into the reused Q-staging region,
//         and orders later iterations' sP/sK/sV WAR hazards.
// LDS (halfs): sP 128x72 @0, sK 64x136 @9216, sV 144x72 @17920.
// ---------------------------------------------------------------------------
#define KSTR 136
#define PSTR 72

__global__ __launch_bounds__(256, 2) void attn_mfma(
    const _Float16* __restrict__ Qp, const _Float16* __restrict__ Kp,
    const _Float16* __restrict__ Vt, _Float16* __restrict__ Aattn)
{
    __shared__ unsigned short lds[28288];
    unsigned short* sP = lds;            // 128 x 72
    unsigned short* sK = lds + 9216;     // 64 x 136
    unsigned short* sV = lds + 17920;    // 144 x 72

    const int t    = threadIdx.x;
    const int w    = t >> 6;
    const int lane = t & 63;
    const int lm   = lane & 15;
    const int quad = lane >> 4;

    const int bid = blockIdx.x;
    const int mt  = bid & 15;
    const int h   = (bid >> 4) & 15;
    const int b   = bid >> 8;

    const _Float16* qb = Qp + (((size_t)(b * NH + h)) * LQ + (size_t)mt * 128) * 128;
    const _Float16* kb = Kp + ((size_t)(b * NH + h)) * SK * 128;
    const _Float16* vb = Vt + ((size_t)(b * NH + h)) * 128 * SK;

    // stage Q tile 128x128 (coalesced) into lds[0..17408), stride KSTR
    #pragma unroll
    for (int p = 0; p < 8; p++) {
        int idx = p * 256 + t;
        int r = idx >> 4, sg = idx & 15;
        *(u16x8*)&lds[r * KSTR + sg * 8] = *(const u16x8*)(qb + (size_t)r * 128 + sg * 8);
    }
    // ones tail rows of sV (disjoint from Q staging region): ALL ones (FIX 1)
    for (int idx = t; idx < 16 * PSTR; idx += 256) {
        sV[128 * PSTR + idx] = 0x3C00;   // fp16 1.0
    }
    __syncthreads();

    // Q -> A-frags in registers (held for whole kernel)
    f16x8 qf[2][4];
    #pragma unroll
    for (int i = 0; i < 2; i++)
        #pragma unroll
        for (int kk = 0; kk < 4; kk++)
            qf[i][kk] = *(const f16x8*)&lds[(w * 32 + i * 16 + lm) * KSTR + kk * 32 + quad * 8];

    // preload K/V tile 0 into regs
    u16x8 kreg[4], vreg[4];
    #pragma unroll
    for (int p = 0; p < 4; p++) {
        int idx = p * 256 + t;
        int r = idx >> 4, sg = idx & 15;
        kreg[p] = *(const u16x8*)(kb + (size_t)r * 128 + sg * 8);
        int rv = idx >> 3, sv = idx & 7;
        vreg[p] = *(const u16x8*)(vb + (size_t)rv * SK + sv * 8);
    }

    f32x4 oacc[2][9] = {};
    float m_st[2][4];
    #pragma unroll
    for (int i = 0; i < 2; i++)
        #pragma unroll
        for (int r = 0; r < 4; r++) m_st[i][r] = -1e30f;

    const float SC2 = ATT_SCALE * 1.44269504f;   // exp2 domain

    for (int it = 0; it < SK / 64; ++it) {
        __syncthreads();                         // FIX 2: also guards it=0 qf reads
        #pragma unroll
        for (int p = 0; p < 4; p++) {
            int idx = p * 256 + t;
            int r = idx >> 4, sg = idx & 15;
            *(u16x8*)&sK[r * KSTR + sg * 8] = kreg[p];
            int rv = idx >> 3, sv = idx & 7;
            *(u16x8*)&sV[rv * PSTR + sv * 8] = vreg[p];
        }
        __syncthreads();

        if (it + 1 < SK / 64) {                  // prefetch next tile
            int s0n = (it + 1) * 64;
            #pragma unroll
            for (int p = 0; p < 4; p++) {
                int idx = p * 256 + t;
                int r = idx >> 4, sg = idx & 15;
                kreg[p] = *(const u16x8*)(kb + (size_t)(s0n + r) * 128 + sg * 8);
                int rv = idx >> 3, sv = idx & 7;
                vreg[p] = *(const u16x8*)(vb + (size_t)rv * SK + s0n + sv * 8);
            }
        }

        // ---- QK^T: wave rows 32 x cols 64, k = 128 (Q from regs) ----
        f32x4 sacc[2][4] = {};
        #pragma unroll
        for (int kk = 0; kk < 4; kk++) {
            f16x8 bfr[4];
            #pragma unroll
            for (int j = 0; j < 4; j++)
                bfr[j] = *(const f16x8*)&sK[(j * 16 + lm) * KSTR + kk * 32 + quad * 8];
            #pragma unroll
            for (int i = 0; i < 2; i++)
                #pragma unroll
                for (int j = 0; j < 4; j++)
                    sacc[i][j] = __builtin_amdgcn_mfma_f32_16x16x32_f16(
                        qf[i][kk], bfr[j], sacc[i][j], 0, 0, 0);
        }

        // ---- online softmax: DPP max, exp2, P->LDS (wave-local) ----
        #pragma unroll
        for (int i = 0; i < 2; i++) {
            #pragma unroll
            for (int r = 0; r < 4; r++) {
                float mx = fmaxf(fmaxf(sacc[i][0][r], sacc[i][1][r]),
                                 fmaxf(sacc[i][2][r], sacc[i][3][r]));
                mx = dpp_max16(mx) * SC2;
                float mnew = fmaxf(m_st[i][r], mx);
                float al = exp2f(m_st[i][r] - mnew);
                m_st[i][r] = mnew;
                int prow = (w * 32 + i * 16 + quad * 4 + r) * PSTR;
                #pragma unroll
                for (int j = 0; j < 4; j++) {
                    float p = exp2f(sacc[i][j][r] * SC2 - mnew);
                    sP[prow + j * 16 + lm] = h2u((_Float16)p);
                }
                #pragma unroll
                for (int j2 = 0; j2 < 9; j2++)
                    oacc[i][j2][r] *= al;
            }
        }

        // ---- PV: O[m][d] += P[m][s] * Vt[d][s]; j2=8 (ones rows) -> l ----
        #pragma unroll
        for (int kk = 0; kk < 2; kk++) {
            f16x8 pf[2], vf[9];
            #pragma unroll
            for (int i = 0; i < 2; i++)
                pf[i] = *(const f16x8*)&sP[(w * 32 + i * 16 + lm) * PSTR + kk * 32 + quad * 8];
            #pragma unroll
            for (int j2 = 0; j2 < 9; j2++)
                vf[j2] = *(const f16x8*)&sV[(j2 * 16 + lm) * PSTR + kk * 32 + quad * 8];
            #pragma unroll
            for (int i = 0; i < 2; i++)
                #pragma unroll
                for (int j2 = 0; j2 < 9; j2++)
                    oacc[i][j2] = __builtin_amdgcn_mfma_f32_16x16x32_f16(
                        pf[i], vf[j2], oacc[i][j2], 0, 0, 0);
        }
    }

    // ---- epilogue: l = oacc[i][8][r] (valid in every lane); normalize ----
    #pragma unroll
    for (int i = 0; i < 2; i++) {
        #pragma unroll
        for (int r = 0; r < 4; r++) {
            float inv = 1.f / oacc[i][8][r];
            int ml = w * 32 + i * 16 + quad * 4 + r;
            size_t row = (size_t)b * LQ + (size_t)mt * 128 + ml;
            #pragma unroll
            for (int j2 = 0; j2 < 8; j2++) {
                int d = j2 * 16 + lm;
                int dcol = (d < HD) ? h * HD + d : CH + h * HD + (d - HD);
                Aattn[row * GK + dcol] = (_Float16)(oacc[i][j2][r] * inv);
            }
        }
    }
}

// ---------------------------------------------------------------------------
extern "C" void kernel_launch(void* const* d_in, const int* in_sizes, int n_in,
                              void* d_out, int out_size, void* d_ws, size_t ws_size,
                              hipStream_t stream)
{
    const float* in_r = (const float*)d_in[0];
    const float* in_i = (const float*)d_in[1];
    const float* cx_r = (const float*)d_in[2];
    const float* cx_i = (const float*)d_in[3];
    const float* wq_r = (const float*)d_in[4];
    const float* wq_i = (const float*)d_in[5];
    const float* wk_r = (const float*)d_in[6];
    const float* wk_i = (const float*)d_in[7];
    const float* wv_r = (const float*)d_in[8];
    const float* wv_i = (const float*)d_in[9];
    const float* wo_r = (const float*)d_in[10];
    const float* wo_i = (const float*)d_in[11];
    const float* bo_r = (const float*)d_in[12];
    const float* bo_i = (const float*)d_in[13];

    _Float16* ws = (_Float16*)d_ws;
    const size_t A_ELEMS = (size_t)MM * GK;
    const size_t B_ELEMS = (size_t)CH * GK;
    const size_t H_ELEMS = (size_t)BB * NH * LQ * 128;

    _Float16* Ain   = ws;
    _Float16* Aattn = ws;                          // alias (Ain dead after qkv GEMM)
    _Float16* Actx  = Ain + A_ELEMS;
    _Float16* Bp    = Actx + A_ELEMS;
    _Float16* Qp    = Bp + 8 * B_ELEMS;
    _Float16* Kp    = Qp + H_ELEMS;
    _Float16* Vt    = Kp + H_ELEMS;

    _Float16* Bq_r = Bp + 0 * B_ELEMS;
    _Float16* Bq_i = Bp + 1 * B_ELEMS;
    _Float16* Bk_r = Bp + 2 * B_ELEMS;
    _Float16* Bk_i = Bp + 3 * B_ELEMS;
    _Float16* Bv_r = Bp + 4 * B_ELEMS;
    _Float16* Bv_i = Bp + 5 * B_ELEMS;
    _Float16* Bo_r = Bp + 6 * B_ELEMS;
    _Float16* Bo_i = Bp + 7 * B_ELEMS;

    float* out = (float*)d_out;
    float* yr = out;
    float* yi = out + (size_t)MM * CH;

    PackXBatch px;
    px.e[0] = { in_r, in_i, Ain  };
    px.e[1] = { cx_r, cx_i, Actx };
    pack_x_kernel<<<dim3(4096, 1, 2), 256, 0, stream>>>(px);

    PackWBatch pw;
    pw.e[0] = { wq_r, wq_i, -1.f, Bq_r };
    pw.e[1] = { wq_i, wq_r,  1.f, Bq_i };
    pw.e[2] = { wk_r, wk_i, -1.f, Bk_r };
    pw.e[3] = { wk_i, wk_r,  1.f, Bk_i };
    pw.e[4] = { wv_r, wv_i, -1.f, Bv_r };
    pw.e[5] = { wv_i, wv_r,  1.f, Bv_i };
    pw.e[6] = { wo_r, wo_i, -1.f, Bo_r };
    pw.e[7] = { wo_i, wo_r,  1.f, Bo_i };
    pack_w_kernel<<<dim3(GK / 32, CH / 32, 8), 256, 0, stream>>>(pw);

    GemmBatch gq;
    gq.e[0] = { Ain,  Bq_r, Qp, nullptr, 0, 0 };
    gq.e[1] = { Ain,  Bq_i, Qp, nullptr, 0, 1 };
    gq.e[2] = { Actx, Bk_r, Kp, nullptr, 0, 0 };
    gq.e[3] = { Actx, Bk_i, Kp, nullptr, 0, 1 };
    gq.e[4] = { Actx, Bv_r, Vt, nullptr, 1, 0 };
    gq.e[5] = { Actx, Bv_i, Vt, nullptr, 1, 1 };
    mfma_cgemm<<<dim3(CH / 128, MM / 128, 6), 256, 0, stream>>>(gq);

    attn_mfma<<<dim3(BB * NH * (LQ / 128)), 256, 0, stream>>>(Qp, Kp, Vt, Aattn);

    GemmBatch go;
    go.e[0] = { Aattn, Bo_r, yr, bo_r, 2, 0 };
    go.e[1] = { Aattn, Bo_i, yi, bo_i, 2, 1 };
    for (int z = 2; z < 6; z++) go.e[z] = go.e[0];
    mfma_cgemm<<<dim3(CH / 128, MM / 128, 2), 256, 0, stream>>>(go);
}